// Round 10
// baseline (709.766 us; speedup 1.0000x reference)
//
#include <hip/hip_runtime.h>
#include <hip/hip_bf16.h>
#include <hip/hip_fp16.h>
#include <cstdint>
#include <cstddef>

#define NNODES 50000
#define NEDGES 800000
#define HID 128
#define NRBF 32
#define NGRAPH 500
#define NB_SCAN 196   // ceil(50000/256)
#define EPB 64        // edges per block in edge_mfma
#define NEBLK (NEDGES / EPB)  // 12500
#define SROWA2 66     // act row stride in uints (264B: q-groups hit distinct bank octets)

typedef __attribute__((ext_vector_type(8))) short short8;
typedef __attribute__((ext_vector_type(4))) float f32x4;

__device__ inline short f2bf(float x) {
  __hip_bfloat16 b = __float2bfloat16(x);
  return *reinterpret_cast<short*>(&b);
}

// single-instruction packed converts (software RNE sequences are 3-8 VALU each)
__device__ inline unsigned int pk_bf16(float a, float b) {
  unsigned int r;
  asm("v_cvt_pk_bf16_f32 %0, %1, %2" : "=v"(r) : "v"(a), "v"(b));
  return r;
}
__device__ inline unsigned int pk_f16(float a, float b) {  // RTZ, lo=a hi=b
  unsigned int r;
  asm("v_cvt_pkrtz_f16_f32 %0, %1, %2" : "=v"(r) : "v"(a), "v"(b));
  return r;
}
// packed f16 add: {lo,hi} + {lo,hi} in one VALU op
__device__ inline unsigned int pk_add_f16(unsigned int a, unsigned int b) {
  unsigned int r;
  asm("v_pk_add_f16 %0, %1, %2" : "=v"(r) : "v"(a), "v"(b));
  return r;
}
// raw transcendentals (exp2/log2 domain; log2e pre-folded into weights)
__device__ inline float aexp2(float x) {
  float r;
  asm("v_exp_f32 %0, %1" : "=v"(r) : "v"(x));
  return r;
}
__device__ inline float aexp2_nabs(float x) {  // exp2(-|x|): free -abs src modifier
  float r;
  asm("v_exp_f32 %0, -abs(%1)" : "=v"(r) : "v"(x));
  return r;
}
__device__ inline float alog2(float x) {
  float r;
  asm("v_log_f32 %0, %1" : "=v"(r) : "v"(x));
  return r;
}

// ------- ALL-layer weight prep in one launch (grid.y = layer) -------
// F-side weights scaled by -log2e, S-side by +log2e: edge kernel then uses
// sigmoid = rcp(1+exp2(fval)) and softplus = ln2*(max(s,0)+log2(1+exp2(-|s|)))
// with the ln2 applied once per run.
// Packed-P rows use the SIGMA channel permutation sigma(c) = (c&15)*8 + (c>>4).
#define SC_F (-1.4426950408889634f)
#define SC_S (1.4426950408889634f)

__global__ void prep_all(
    const float* __restrict__ Wf0, const float* __restrict__ Ws0,
    const float* __restrict__ bf0, const float* __restrict__ bs0,
    const float* __restrict__ Wf1, const float* __restrict__ Ws1,
    const float* __restrict__ bf1, const float* __restrict__ bs1,
    const float* __restrict__ Wf2, const float* __restrict__ Ws2,
    const float* __restrict__ bf2, const float* __restrict__ bs2,
    unsigned short* __restrict__ WtB3, unsigned short* __restrict__ WnB3,
    float* __restrict__ biasv3) {
  const int l = blockIdx.y;
  const float* Wf = (l == 0) ? Wf0 : ((l == 1) ? Wf1 : Wf2);
  const float* Ws = (l == 0) ? Ws0 : ((l == 1) ? Ws1 : Ws2);
  const float* bf = (l == 0) ? bf0 : ((l == 1) ? bf1 : bf2);
  const float* bs = (l == 0) ? bs0 : ((l == 1) ? bs1 : bs2);
  unsigned short* WtB = WtB3 + l * 8192;
  unsigned short* WnB = WnB3 + l * 65536;
  float* biasv = biasv3 + l * 256;

  int i0 = blockIdx.x * blockDim.x + threadIdx.x;
  if (i0 < 8192) {
    int i = i0;
    int j = i & 7, lane = (i >> 3) & 63, t = i >> 9;
    int q = lane >> 4, n = lane & 15;
    int k = q * 8 + j, c = (t & 7) * 16 + n;
    const float* W = (t < 8) ? Wf : Ws;
    const float sc = (t < 8) ? SC_F : SC_S;
    WtB[i] = (unsigned short)f2bf(W[(size_t)(256 + k) * HID + c] * sc);
  } else if (i0 < 8192 + 65536) {
    int i = i0 - 8192;
    int j = i & 7;
    int lane = (i >> 3) & 63;
    int tk = (i >> 9) & 3;
    int tc = i >> 11;  // 0..31
    int q = lane >> 4, n = lane & 15;
    int k = tk * 32 + q * 8 + j;
    float v;
    int which;
    if (tc < 16) {
      // dst half (W rows 0..127), non-interleaved: tile 2g=F, 2g+1=S, c=g*16+n
      int g = tc >> 1;
      which = tc & 1;
      int c = g * 16 + n;
      const float* W = which ? Ws : Wf;
      v = W[(size_t)k * HID + c];
    } else {
      // src half (W rows 128..255), same layout
      int g = (tc - 16) >> 1;
      which = (tc - 16) & 1;
      int c = g * 16 + n;
      const float* W = which ? Ws : Wf;
      v = W[(size_t)(128 + k) * HID + c];
    }
    WnB[i] = (unsigned short)f2bf(v * (which ? SC_S : SC_F));
    if (i < 256) {
      int c2 = i >> 1, w2 = i & 1;
      biasv[i] = w2 ? bs[c2] * SC_S : bf[c2] * SC_F;
    }
  }
}

// ---------------- CSR build: histogram -> scan -> scatter(+eattr pack) ----------------
__global__ void deg_hist(const int* __restrict__ dst, int* __restrict__ deg) {
  int e = blockIdx.x * blockDim.x + threadIdx.x;
  if (e < NEDGES) atomicAdd(&deg[dst[e]], 1);
}

__global__ __launch_bounds__(256) void scan_block(const int* __restrict__ deg, int* __restrict__ bsum) {
  __shared__ int s[256];
  int i = blockIdx.x * 256 + threadIdx.x;
  s[threadIdx.x] = (i < NNODES) ? deg[i] : 0;
  __syncthreads();
  for (int off = 128; off > 0; off >>= 1) {
    if (threadIdx.x < off) s[threadIdx.x] += s[threadIdx.x + off];
    __syncthreads();
  }
  if (threadIdx.x == 0) bsum[blockIdx.x] = s[0];
}

__global__ __launch_bounds__(256) void scan_top(const int* __restrict__ bsum,
                                                int* __restrict__ bpre) {
  __shared__ int s[256];
  int t = threadIdx.x;
  int v = (t < NB_SCAN) ? bsum[t] : 0;
  s[t] = v;
  __syncthreads();
  for (int off = 1; off < 256; off <<= 1) {
    int u = (t >= off) ? s[t - off] : 0;
    __syncthreads();
    s[t] += u;
    __syncthreads();
  }
  if (t < NB_SCAN) bpre[t] = s[t] - v;
}

__global__ __launch_bounds__(256) void scan_final(const int* __restrict__ deg,
                                                  const int* __restrict__ bpre,
                                                  int* __restrict__ cursor) {
  __shared__ int s[256];
  int i = blockIdx.x * 256 + threadIdx.x;
  int v = (i < NNODES) ? deg[i] : 0;
  s[threadIdx.x] = v;
  __syncthreads();
  for (int off = 1; off < 256; off <<= 1) {
    int t = (threadIdx.x >= off) ? s[threadIdx.x - off] : 0;
    __syncthreads();
    s[threadIdx.x] += t;
    __syncthreads();
  }
  if (i < NNODES) cursor[i] = bpre[blockIdx.x] + s[threadIdx.x] - v;  // exclusive
}

// scatter + fused eattr->bf16 pack in sorted order
__global__ void scatter_edges_pack(const int* __restrict__ src, const int* __restrict__ dst,
                                   const float* __restrict__ eattr, int* __restrict__ cursor,
                                   int2* __restrict__ se2, unsigned short* __restrict__ eaB) {
  int e = blockIdx.x * blockDim.x + threadIdx.x;
  if (e >= NEDGES) return;
  int d = dst[e];
  int pos = atomicAdd(&cursor[d], 1);
  se2[pos] = make_int2(src[e], d);
  const float* ep = eattr + (size_t)e * NRBF;
  unsigned short* op = eaB + (size_t)pos * NRBF;
#pragma unroll
  for (int part = 0; part < 4; ++part) {
    const float4 v0 = *(const float4*)&ep[part * 8];
    const float4 v1 = *(const float4*)&ep[part * 8 + 4];
    uint4 o;
    o.x = pk_bf16(v0.x, v0.y);
    o.y = pk_bf16(v0.z, v0.w);
    o.z = pk_bf16(v1.x, v1.y);
    o.w = pk_bf16(v1.z, v1.w);
    *(uint4*)&op[part * 8] = o;
  }
}

// ---------------- node MFMA GEMM, fused embed (mode 0) / relu-add+agg-zero (mode 1) ---
// h16[n][64]: packed f16 channel pairs (2c,2c+1) -- halves h HBM traffic.
// Pdst[n][128] / Psrc[n][128]: uint packed fp16 {f,s}, SIGMA channel order.
// mode 1 also ZEROES agg rows after consuming them.
__global__ __launch_bounds__(256) void node_mfma(
    const int* __restrict__ x, const float* __restrict__ emb,
    unsigned int* __restrict__ h16, float* __restrict__ agg,
    const unsigned short* __restrict__ WnB, const float* __restrict__ biasv,
    unsigned int* __restrict__ Pdst, unsigned int* __restrict__ Psrc, int mode, int N) {
  const int tid = threadIdx.x;
  const int wv = tid >> 6;
  const int lane = tid & 63;
  const int q = lane >> 4;
  const int n = lane & 15;
  const int nb = blockIdx.x * 32 + (wv >> 1) * 16;
  const int srcwave = wv & 1;
  const int ctile0 = srcwave * 16;

  const bool valid = (nb + n) < N;
  int anode = nb + n;
  if (anode >= N) anode = N - 1;
  unsigned int* hp = h16 + (size_t)anode * 64;

  short8 a[4];
  if (mode == 0) {
    const float* ep = emb + (size_t)x[anode] * HID;
#pragma unroll
    for (int kt = 0; kt < 4; ++kt) {
      const float4 e0 = *(const float4*)&ep[kt * 32 + q * 8];
      const float4 e1 = *(const float4*)&ep[kt * 32 + q * 8 + 4];
      if (valid && !srcwave) {
        uint4 hv;
        hv.x = pk_f16(e0.x, e0.y);
        hv.y = pk_f16(e0.z, e0.w);
        hv.z = pk_f16(e1.x, e1.y);
        hv.w = pk_f16(e1.z, e1.w);
        *(uint4*)&hp[kt * 16 + q * 4] = hv;
      }
      union { short8 s8; unsigned int u32[4]; } au;
      au.u32[0] = pk_bf16(e0.x, e0.y);
      au.u32[1] = pk_bf16(e0.z, e0.w);
      au.u32[2] = pk_bf16(e1.x, e1.y);
      au.u32[3] = pk_bf16(e1.z, e1.w);
      a[kt] = au.s8;
    }
  } else {
    float* ap = agg + (size_t)anode * HID;
    uint4 hnew[4];
#pragma unroll
    for (int kt = 0; kt < 4; ++kt) {
      const uint4 hv = *(const uint4*)&hp[kt * 16 + q * 4];
      const float2 h0 = __half22float2(*reinterpret_cast<const __half2*>(&hv.x));
      const float2 h1 = __half22float2(*reinterpret_cast<const __half2*>(&hv.y));
      const float2 h2 = __half22float2(*reinterpret_cast<const __half2*>(&hv.z));
      const float2 h3 = __half22float2(*reinterpret_cast<const __half2*>(&hv.w));
      const float4 g0 = *(const float4*)&ap[kt * 32 + q * 8];
      const float4 g1 = *(const float4*)&ap[kt * 32 + q * 8 + 4];
      const float e0 = fmaxf(h0.x + g0.x, 0.f);
      const float e1 = fmaxf(h0.y + g0.y, 0.f);
      const float e2 = fmaxf(h1.x + g0.z, 0.f);
      const float e3 = fmaxf(h1.y + g0.w, 0.f);
      const float e4 = fmaxf(h2.x + g1.x, 0.f);
      const float e5 = fmaxf(h2.y + g1.y, 0.f);
      const float e6 = fmaxf(h3.x + g1.z, 0.f);
      const float e7 = fmaxf(h3.y + g1.w, 0.f);
      hnew[kt].x = pk_f16(e0, e1);
      hnew[kt].y = pk_f16(e2, e3);
      hnew[kt].z = pk_f16(e4, e5);
      hnew[kt].w = pk_f16(e6, e7);
      union { short8 s8; unsigned int u32[4]; } au;
      au.u32[0] = pk_bf16(e0, e1);
      au.u32[1] = pk_bf16(e2, e3);
      au.u32[2] = pk_bf16(e4, e5);
      au.u32[3] = pk_bf16(e6, e7);
      a[kt] = au.s8;
    }
    __syncthreads();  // all h/agg reads done before in-place writes (race fix R11)
    if (valid && !srcwave) {
      const float4 z4 = {0.f, 0.f, 0.f, 0.f};
#pragma unroll
      for (int kt = 0; kt < 4; ++kt) {
        *(uint4*)&hp[kt * 16 + q * 4] = hnew[kt];
        *(float4*)&ap[kt * 32 + q * 8] = z4;       // re-zero agg for next layer
        *(float4*)&ap[kt * 32 + q * 8 + 4] = z4;
      }
    }
  }

  const short8* WnB8 = (const short8*)WnB;
  f32x4 acc[16];
#pragma unroll
  for (int tc = 0; tc < 16; ++tc) acc[tc] = (f32x4){0.f, 0.f, 0.f, 0.f};

#pragma unroll
  for (int tc = 0; tc < 16; ++tc) {
#pragma unroll
    for (int kt = 0; kt < 4; ++kt) {
      short8 b = WnB8[((size_t)((ctile0 + tc) * 4 + kt)) * 64 + lane];
      acc[tc] = __builtin_amdgcn_mfma_f32_16x16x32_bf16(a[kt], b, acc[tc], 0, 0, 0);
    }
  }

  // SIGMA epilogue: lane (q,n) emits channels c=g2*16+n for g2=0..7 at positions
  // n*8+g2 -> two contiguous uint4 stores per node-row.
  if (!srcwave) {
#pragma unroll
    for (int r = 0; r < 4; ++r) {
      const int node = nb + q * 4 + r;
      if (node < N) {
        unsigned int o[8];
#pragma unroll
        for (int g2 = 0; g2 < 8; ++g2) {
          const int c = g2 * 16 + n;
          o[g2] = pk_f16(acc[2 * g2][r] + biasv[2 * c], acc[2 * g2 + 1][r] + biasv[2 * c + 1]);
        }
        *(uint4*)&Pdst[(size_t)node * 128 + n * 8] = make_uint4(o[0], o[1], o[2], o[3]);
        *(uint4*)&Pdst[(size_t)node * 128 + n * 8 + 4] = make_uint4(o[4], o[5], o[6], o[7]);
      }
    }
  } else {
#pragma unroll
    for (int r = 0; r < 4; ++r) {
      const int node = nb + q * 4 + r;
      if (node < N) {
        unsigned int o[8];
#pragma unroll
        for (int g2 = 0; g2 < 8; ++g2) {
          o[g2] = pk_f16(acc[2 * g2][r], acc[2 * g2 + 1][r]);
        }
        *(uint4*)&Psrc[(size_t)node * 128 + n * 8] = make_uint4(o[0], o[1], o[2], o[3]);
        *(uint4*)&Psrc[(size_t)node * 128 + n * 8 + 4] = make_uint4(o[4], o[5], o[6], o[7]);
      }
    }
  }
}

// ---------------- MFMA edge kernel, EPB=64 / 256 threads ----------------
// Phase 2: contiguous 32B P gathers -> spd = ps+pd (f16); unpacked spd seeds the
// MFMA C-operand; fused activation; paired f16 act -> LDS.
// Phase 3 (edge-balanced): wave wv owns edges [wv*16, wv*16+16) and flushes
// maximal same-dst runs. Runs touching a wave/block boundary -> atomicAdd;
// interior runs -> plain store (dst rows are globally contiguous => exactly one
// writer). Run boundaries are wave-uniform (dstL shared) -> no divergence.
__global__ __launch_bounds__(256) void edge_mfma(
    const unsigned int* __restrict__ Pdst, const unsigned int* __restrict__ Psrc,
    const unsigned short* __restrict__ eaB, const unsigned short* __restrict__ WtB,
    const int2* __restrict__ se2, float* __restrict__ agg) {
  __shared__ unsigned int actL[EPB * SROWA2];   // 16.5 KB (64 pairs/edge)
  __shared__ int dstL[EPB];

  const int tid = threadIdx.x;
  const int base = blockIdx.x * EPB;
  const int lane = tid & 63;
  const int wv = tid >> 6;        // 0..3
  const int q = lane >> 4;
  const int n = lane & 15;
  const int rowb = wv * 16 + q * 4;

  // ---- Phase 1: stage dst ids (consumed by phase 3 after the barrier) ----
  if (tid < EPB) dstL[tid] = se2[base + tid].y;

  // ---- Phase 2: contiguous P gathers -> spd; C-seeded MFMA; fused activation ----
  const short8 afrag = *(const short8*)&eaB[(size_t)(base + wv * 16 + n) * 32 + q * 8];

  uint4 spd[8];  // [r*2 + half]: ps+pd for this lane's 8 channels of 4 edges
#pragma unroll
  for (int r = 0; r < 4; ++r) {
    const int2 sd = se2[base + rowb + r];
    const uint4* ps4 = (const uint4*)(Psrc + (size_t)sd.x * 128 + n * 8);
    const uint4* pd4 = (const uint4*)(Pdst + (size_t)sd.y * 128 + n * 8);
    const uint4 s0 = ps4[0], s1 = ps4[1];
    const uint4 d0 = pd4[0], d1 = pd4[1];
    spd[r * 2].x = pk_add_f16(s0.x, d0.x);
    spd[r * 2].y = pk_add_f16(s0.y, d0.y);
    spd[r * 2].z = pk_add_f16(s0.z, d0.z);
    spd[r * 2].w = pk_add_f16(s0.w, d0.w);
    spd[r * 2 + 1].x = pk_add_f16(s1.x, d1.x);
    spd[r * 2 + 1].y = pk_add_f16(s1.y, d1.y);
    spd[r * 2 + 1].z = pk_add_f16(s1.z, d1.z);
    spd[r * 2 + 1].w = pk_add_f16(s1.w, d1.w);
  }

  const short8* WtB8 = (const short8*)WtB;
  float va[4][4];   // t<4 products, statically indexed (fully unrolled)
#pragma unroll
  for (int t = 0; t < 8; ++t) {
    f32x4 cinf, cins;
#pragma unroll
    for (int r = 0; r < 4; ++r) {
      const uint4 v = spd[r * 2 + (t >> 2)];
      const unsigned int sv = ((t & 3) == 0) ? v.x : ((t & 3) == 1) ? v.y
                             : ((t & 3) == 2) ? v.z : v.w;
      const float2 pz = __half22float2(*reinterpret_cast<const __half2*>(&sv));
      cinf[r] = pz.x;
      cins[r] = pz.y;
    }
    short8 bfr = WtB8[t * 64 + lane];
    short8 bsr = WtB8[(8 + t) * 64 + lane];
    f32x4 cf = __builtin_amdgcn_mfma_f32_16x16x32_bf16(afrag, bfr, cinf, 0, 0, 0);
    f32x4 cs = __builtin_amdgcn_mfma_f32_16x16x32_bf16(afrag, bsr, cins, 0, 0, 0);
#pragma unroll
    for (int r = 0; r < 4; ++r) {
      const float sig = __builtin_amdgcn_rcpf(1.f + aexp2(cf[r]));
      const float sp = fmaxf(cs[r], 0.f) + alog2(1.f + aexp2_nabs(cs[r]));
      const float av = sig * sp;
      if (t < 4) {
        va[t][r] = av;
      } else {
        actL[(rowb + r) * SROWA2 + (t - 4) * 16 + n] = pk_f16(va[t - 4][r], av);
      }
    }
  }
  __syncthreads();

  // ---- Phase 3: edge-balanced segmented runs; lane owns channels (lane, lane+64) ----
  const int j0 = wv * 16;
  const int j1 = j0 + 16;
  int dcur = dstL[j0];
  bool openL = (j0 == 0) || (dstL[j0 - 1] == dcur);  // run may extend left (or prev block)
  float a0 = 0.f, a1 = 0.f;
  unsigned int av_nx = actL[j0 * SROWA2 + lane];
  for (int j = j0; j < j1; ++j) {
    const int dj = dstL[j];
    if (dj != dcur) {  // wave-uniform branch: flush closed-right run
      const int d = __builtin_amdgcn_readfirstlane(dcur);
      float* ap0 = agg + (size_t)d * HID + lane;
      const float f0 = a0 * 0.6931471805599453f;
      const float f1 = a1 * 0.6931471805599453f;
      if (openL) {
        atomicAdd(ap0, f0);
        atomicAdd(ap0 + 64, f1);
      } else {
        ap0[0] = f0;
        ap0[64] = f1;
      }
      dcur = dj;
      openL = false;
      a0 = 0.f;
      a1 = 0.f;
    }
    const unsigned int av = av_nx;
    const int jn = (j + 1 < j1) ? (j + 1) : j;
    av_nx = actL[jn * SROWA2 + lane];
    const float2 a2 = __half22float2(*reinterpret_cast<const __half2*>(&av));
    a0 += a2.x;
    a1 += a2.y;
  }
  {
    const bool openR = (j1 == EPB) || (dstL[j1] == dcur);  // run may extend right (or next block)
    const int d = __builtin_amdgcn_readfirstlane(dcur);
    float* ap0 = agg + (size_t)d * HID + lane;
    const float f0 = a0 * 0.6931471805599453f;
    const float f1 = a1 * 0.6931471805599453f;
    if (openL || openR) {
      atomicAdd(ap0, f0);
      atomicAdd(ap0 + 64, f1);
    } else {
      ap0[0] = f0;
      ap0[64] = f1;
    }
  }
}

// ---------------- pooling: batch is SORTED -> run-detection, few atomics ----------------
__global__ __launch_bounds__(256) void pool_kernel(
    const unsigned int* __restrict__ h16, const float* __restrict__ agg,
    const int* __restrict__ batch, float* __restrict__ sums, float* __restrict__ counts) {
  __shared__ int gidL[64];
  __shared__ int grpS[65];
  __shared__ int sndP;

  const int tid = threadIdx.x;
  const int lane = tid & 63;
  const int wv = tid >> 6;
  const int nb = blockIdx.x * 64;
  int nvalid = NNODES - nb;
  if (nvalid > 64) nvalid = 64;

  if (tid < 64) {
    int node = nb + tid;
    int g = batch[node < NNODES ? node : NNODES - 1];
    gidL[tid] = g;
    int gprev = __shfl_up(g, 1);
    int flag = (tid < nvalid && (tid == 0 || gprev != g)) ? 1 : 0;
    unsigned long long mask = __ballot(flag);
    int slot = __popcll(mask & ((lane == 63) ? ~0ull : ((1ull << (lane + 1)) - 1))) - 1;
    if (flag) grpS[slot] = tid;
    if (tid == 0) {
      int nd = __popcll(mask);
      sndP = nd;
      grpS[nd] = nvalid;
    }
  }
  __syncthreads();

  const int nd = sndP;
  for (int g = wv; g < nd; g += 4) {
    const int jb = grpS[g];
    const int je = grpS[g + 1];
    const int gid = __builtin_amdgcn_readfirstlane(gidL[jb]);
    float a0 = 0.f, a1 = 0.f;
    for (int j = jb; j < je; ++j) {
      const unsigned int hv = h16[(size_t)(nb + j) * 64 + lane];
      const float2 hf = __half22float2(*reinterpret_cast<const __half2*>(&hv));
      const float2 av = *(const float2*)&agg[(size_t)(nb + j) * HID + 2 * lane];
      a0 += fmaxf(hf.x + av.x, 0.f);
      a1 += fmaxf(hf.y + av.y, 0.f);
    }
    float* sp = sums + (size_t)gid * HID + 2 * lane;
    const bool bnd = (g == 0 || g == nd - 1);
    if (bnd) {
      atomicAdd(sp, a0);
      atomicAdd(sp + 1, a1);
    } else {
      *(float2*)sp = make_float2(a0, a1);
    }
    if (lane == 0) {
      if (bnd) atomicAdd(&counts[gid], (float)(je - jb));
      else counts[gid] = (float)(je - jb);
    }
  }
}

// ---------------- out[g] = (sums[g]/max(cnt,1)) @ Wlin + blin ----------------
__global__ __launch_bounds__(128) void final_kernel(
    const float* __restrict__ sums, const float* __restrict__ counts,
    const float* __restrict__ Wlin, const float* __restrict__ blin,
    float* __restrict__ out) {
  int g = blockIdx.x;
  int c = threadIdx.x;
  __shared__ float pool[HID];
  float cnt = counts[g];
  cnt = cnt > 1.f ? cnt : 1.f;
  pool[c] = sums[(size_t)g * HID + c] / cnt;
  __syncthreads();
  float acc = blin[c];
#pragma unroll 8
  for (int k = 0; k < HID; ++k) acc = fmaf(pool[k], Wlin[k * HID + c], acc);
  out[(size_t)g * HID + c] = acc;
}

extern "C" void kernel_launch(void* const* d_in, const int* in_sizes, int n_in,
                              void* d_out, int out_size, void* d_ws, size_t ws_size,
                              hipStream_t stream) {
  const int* x = (const int*)d_in[0];
  const int* eidx = (const int*)d_in[1];
  const float* eattr = (const float*)d_in[2];
  const int* batch = (const int*)d_in[3];
  const float* emb = (const float*)d_in[4];
  const float* Wf[3] = {(const float*)d_in[5], (const float*)d_in[9], (const float*)d_in[13]};
  const float* bf[3] = {(const float*)d_in[6], (const float*)d_in[10], (const float*)d_in[14]};
  const float* Ws[3] = {(const float*)d_in[7], (const float*)d_in[11], (const float*)d_in[15]};
  const float* bs[3] = {(const float*)d_in[8], (const float*)d_in[12], (const float*)d_in[16]};
  const float* Wlin = (const float*)d_in[17];
  const float* blin = (const float*)d_in[18];
  const int* srcp = eidx;
  const int* dstp = eidx + NEDGES;

  float* wsf = (float*)d_ws;
  float* hF = wsf;                                   // N*128 reserved (N*64 uints used)
  float* PdstF = hF + (size_t)NNODES * HID;          // N*256 reserved (N*128 uints used)
  float* agg = PdstF + (size_t)NNODES * 256;         // N*128
  float* sums = agg + (size_t)NNODES * HID;          // 500*128
  float* counts = sums + (size_t)NGRAPH * HID;       // 500
  float* biasv3 = counts + NGRAPH;                   // 3*256
  unsigned int* Psrc = (unsigned int*)(biasv3 + 768);  // N*128 uint packed fp16
  unsigned short* WtB3 = (unsigned short*)(Psrc + (size_t)NNODES * 128);  // 3*8192
  unsigned short* WnB3 = WtB3 + 3 * 8192;            // 3*65536
  unsigned short* eaB = WnB3 + 3 * 65536;            // NEDGES*32 bf16
  int2* se2 = (int2*)(eaB + (size_t)NEDGES * 32);    // 800000 int2
  int* deg = (int*)(se2 + NEDGES);                   // 50000
  int* cursor = deg + NNODES;                        // 50000
  int* bsum = cursor + NNODES;                       // 196
  int* bpre = bsum + NB_SCAN;                        // 196
  unsigned int* Pdst = (unsigned int*)PdstF;         // N*128 uint packed fp16
  unsigned int* h16 = (unsigned int*)hF;             // N*64 uint packed f16 pairs

  // --- weight prep (all 3 layers, one launch) ---
  dim3 pgrid(288, 3);
  prep_all<<<pgrid, 256, 0, stream>>>(Wf[0], Ws[0], bf[0], bs[0],
                                      Wf[1], Ws[1], bf[1], bs[1],
                                      Wf[2], Ws[2], bf[2], bs[2],
                                      WtB3, WnB3, biasv3);

  // --- CSR build (edges layer-invariant: once per call) ---
  hipMemsetAsync(deg, 0, NNODES * sizeof(int), stream);
  deg_hist<<<(NEDGES + 255) / 256, 256, 0, stream>>>(dstp, deg);
  scan_block<<<NB_SCAN, 256, 0, stream>>>(deg, bsum);
  scan_top<<<1, 256, 0, stream>>>(bsum, bpre);
  scan_final<<<NB_SCAN, 256, 0, stream>>>(deg, bpre, cursor);
  scatter_edges_pack<<<(NEDGES + 255) / 256, 256, 0, stream>>>(srcp, dstp, eattr, cursor,
                                                               se2, eaB);

  // single agg zero: layer>=1 re-zeroed inside node_mfma mode 1
  hipMemsetAsync(agg, 0, (size_t)NNODES * HID * sizeof(float), stream);

  const int nblk_node = (NNODES + 31) / 32;  // 1563
  for (int l = 0; l < 3; ++l) {
    node_mfma<<<nblk_node, 256, 0, stream>>>(x, emb, h16, agg, WnB3 + l * 65536,
                                             biasv3 + l * 256, Pdst, Psrc,
                                             l > 0 ? 1 : 0, NNODES);
    edge_mfma<<<NEBLK, 256, 0, stream>>>(Pdst, Psrc, eaB, WtB3 + l * 8192, se2, agg);
  }

  hipMemsetAsync(sums, 0, (size_t)(NGRAPH * HID + NGRAPH) * sizeof(float), stream);
  pool_kernel<<<(NNODES + 63) / 64, 256, 0, stream>>>(h16, agg, batch, sums, counts);
  final_kernel<<<NGRAPH, 128, 0, stream>>>(sums, counts, Wlin, blin, (float*)d_out);
}

// Round 11
// 700.010 us; speedup vs baseline: 1.0139x; 1.0139x over previous
//
#include <hip/hip_runtime.h>
#include <hip/hip_bf16.h>
#include <hip/hip_fp16.h>
#include <cstdint>
#include <cstddef>

#define NNODES 50000
#define NEDGES 800000
#define HID 128
#define NRBF 32
#define NGRAPH 500
#define NB_SCAN 196   // ceil(50000/256)
#define EPB 64        // edges per block in edge_mfma
#define NEBLK (NEDGES / EPB)  // 12500
#define SROWA2 66     // act row stride in uints (264B: q-groups hit distinct bank octets)

typedef __attribute__((ext_vector_type(8))) short short8;
typedef __attribute__((ext_vector_type(4))) float f32x4;

__device__ inline short f2bf(float x) {
  __hip_bfloat16 b = __float2bfloat16(x);
  return *reinterpret_cast<short*>(&b);
}

// single-instruction packed converts (software RNE sequences are 3-8 VALU each)
__device__ inline unsigned int pk_bf16(float a, float b) {
  unsigned int r;
  asm("v_cvt_pk_bf16_f32 %0, %1, %2" : "=v"(r) : "v"(a), "v"(b));
  return r;
}
__device__ inline unsigned int pk_f16(float a, float b) {  // RTZ, lo=a hi=b
  unsigned int r;
  asm("v_cvt_pkrtz_f16_f32 %0, %1, %2" : "=v"(r) : "v"(a), "v"(b));
  return r;
}
// packed f16 add: {lo,hi} + {lo,hi} in one VALU op
__device__ inline unsigned int pk_add_f16(unsigned int a, unsigned int b) {
  unsigned int r;
  asm("v_pk_add_f16 %0, %1, %2" : "=v"(r) : "v"(a), "v"(b));
  return r;
}
// raw transcendentals (exp2/log2 domain; log2e pre-folded into weights)
__device__ inline float aexp2(float x) {
  float r;
  asm("v_exp_f32 %0, %1" : "=v"(r) : "v"(x));
  return r;
}
__device__ inline float aexp2_nabs(float x) {  // exp2(-|x|): free -abs src modifier
  float r;
  asm("v_exp_f32 %0, -abs(%1)" : "=v"(r) : "v"(x));
  return r;
}
__device__ inline float alog2(float x) {
  float r;
  asm("v_log_f32 %0, %1" : "=v"(r) : "v"(x));
  return r;
}

// ------- ALL-layer weight prep in one launch (grid.y = layer) -------
// F-side weights scaled by -log2e, S-side by +log2e: edge kernel then uses
// sigmoid = rcp(1+exp2(fval)) and softplus = ln2*(max(s,0)+log2(1+exp2(-|s|)))
// with the ln2 applied once per group.
// Packed-P rows use the SIGMA channel permutation sigma(c) = (c&15)*8 + (c>>4).
#define SC_F (-1.4426950408889634f)
#define SC_S (1.4426950408889634f)

__global__ void prep_all(
    const float* __restrict__ Wf0, const float* __restrict__ Ws0,
    const float* __restrict__ bf0, const float* __restrict__ bs0,
    const float* __restrict__ Wf1, const float* __restrict__ Ws1,
    const float* __restrict__ bf1, const float* __restrict__ bs1,
    const float* __restrict__ Wf2, const float* __restrict__ Ws2,
    const float* __restrict__ bf2, const float* __restrict__ bs2,
    unsigned short* __restrict__ WtB3, unsigned short* __restrict__ WnB3,
    float* __restrict__ biasv3) {
  const int l = blockIdx.y;
  const float* Wf = (l == 0) ? Wf0 : ((l == 1) ? Wf1 : Wf2);
  const float* Ws = (l == 0) ? Ws0 : ((l == 1) ? Ws1 : Ws2);
  const float* bf = (l == 0) ? bf0 : ((l == 1) ? bf1 : bf2);
  const float* bs = (l == 0) ? bs0 : ((l == 1) ? bs1 : bs2);
  unsigned short* WtB = WtB3 + l * 8192;
  unsigned short* WnB = WnB3 + l * 65536;
  float* biasv = biasv3 + l * 256;

  int i0 = blockIdx.x * blockDim.x + threadIdx.x;
  if (i0 < 8192) {
    int i = i0;
    int j = i & 7, lane = (i >> 3) & 63, t = i >> 9;
    int q = lane >> 4, n = lane & 15;
    int k = q * 8 + j, c = (t & 7) * 16 + n;
    const float* W = (t < 8) ? Wf : Ws;
    const float sc = (t < 8) ? SC_F : SC_S;
    WtB[i] = (unsigned short)f2bf(W[(size_t)(256 + k) * HID + c] * sc);
  } else if (i0 < 8192 + 65536) {
    int i = i0 - 8192;
    int j = i & 7;
    int lane = (i >> 3) & 63;
    int tk = (i >> 9) & 3;
    int tc = i >> 11;  // 0..31
    int q = lane >> 4, n = lane & 15;
    int k = tk * 32 + q * 8 + j;
    float v;
    int which;
    if (tc < 16) {
      // dst half (W rows 0..127), non-interleaved: tile 2g=F, 2g+1=S, c=g*16+n
      int g = tc >> 1;
      which = tc & 1;
      int c = g * 16 + n;
      const float* W = which ? Ws : Wf;
      v = W[(size_t)k * HID + c];
    } else {
      // src half (W rows 128..255), same layout
      int g = (tc - 16) >> 1;
      which = (tc - 16) & 1;
      int c = g * 16 + n;
      const float* W = which ? Ws : Wf;
      v = W[(size_t)(128 + k) * HID + c];
    }
    WnB[i] = (unsigned short)f2bf(v * (which ? SC_S : SC_F));
    if (i < 256) {
      int c2 = i >> 1, w2 = i & 1;
      biasv[i] = w2 ? bs[c2] * SC_S : bf[c2] * SC_F;
    }
  }
}

// ---------------- CSR build: histogram -> scan -> scatter(+eattr pack) ----------------
__global__ void deg_hist(const int* __restrict__ dst, int* __restrict__ deg) {
  int e = blockIdx.x * blockDim.x + threadIdx.x;
  if (e < NEDGES) atomicAdd(&deg[dst[e]], 1);
}

__global__ __launch_bounds__(256) void scan_block(const int* __restrict__ deg, int* __restrict__ bsum) {
  __shared__ int s[256];
  int i = blockIdx.x * 256 + threadIdx.x;
  s[threadIdx.x] = (i < NNODES) ? deg[i] : 0;
  __syncthreads();
  for (int off = 128; off > 0; off >>= 1) {
    if (threadIdx.x < off) s[threadIdx.x] += s[threadIdx.x + off];
    __syncthreads();
  }
  if (threadIdx.x == 0) bsum[blockIdx.x] = s[0];
}

__global__ __launch_bounds__(256) void scan_top(const int* __restrict__ bsum,
                                                int* __restrict__ bpre) {
  __shared__ int s[256];
  int t = threadIdx.x;
  int v = (t < NB_SCAN) ? bsum[t] : 0;
  s[t] = v;
  __syncthreads();
  for (int off = 1; off < 256; off <<= 1) {
    int u = (t >= off) ? s[t - off] : 0;
    __syncthreads();
    s[t] += u;
    __syncthreads();
  }
  if (t < NB_SCAN) bpre[t] = s[t] - v;
}

__global__ __launch_bounds__(256) void scan_final(const int* __restrict__ deg,
                                                  const int* __restrict__ bpre,
                                                  int* __restrict__ cursor) {
  __shared__ int s[256];
  int i = blockIdx.x * 256 + threadIdx.x;
  int v = (i < NNODES) ? deg[i] : 0;
  s[threadIdx.x] = v;
  __syncthreads();
  for (int off = 1; off < 256; off <<= 1) {
    int t = (threadIdx.x >= off) ? s[threadIdx.x - off] : 0;
    __syncthreads();
    s[threadIdx.x] += t;
    __syncthreads();
  }
  if (i < NNODES) cursor[i] = bpre[blockIdx.x] + s[threadIdx.x] - v;  // exclusive
}

// scatter + fused eattr->bf16 pack in sorted order
__global__ void scatter_edges_pack(const int* __restrict__ src, const int* __restrict__ dst,
                                   const float* __restrict__ eattr, int* __restrict__ cursor,
                                   int2* __restrict__ se2, unsigned short* __restrict__ eaB) {
  int e = blockIdx.x * blockDim.x + threadIdx.x;
  if (e >= NEDGES) return;
  int d = dst[e];
  int pos = atomicAdd(&cursor[d], 1);
  se2[pos] = make_int2(src[e], d);
  const float* ep = eattr + (size_t)e * NRBF;
  unsigned short* op = eaB + (size_t)pos * NRBF;
#pragma unroll
  for (int part = 0; part < 4; ++part) {
    const float4 v0 = *(const float4*)&ep[part * 8];
    const float4 v1 = *(const float4*)&ep[part * 8 + 4];
    uint4 o;
    o.x = pk_bf16(v0.x, v0.y);
    o.y = pk_bf16(v0.z, v0.w);
    o.z = pk_bf16(v1.x, v1.y);
    o.w = pk_bf16(v1.z, v1.w);
    *(uint4*)&op[part * 8] = o;
  }
}

// ---------------- node MFMA GEMM, fused embed (mode 0) / relu-add+agg-zero (mode 1) ---
// h16[n][64]: packed f16 channel pairs (2c,2c+1) -- halves h HBM traffic.
// Pdst[n][128] / Psrc[n][128]: uint packed fp16 {f,s}, SIGMA channel order.
// mode 1 also ZEROES agg rows after consuming them.
__global__ __launch_bounds__(256) void node_mfma(
    const int* __restrict__ x, const float* __restrict__ emb,
    unsigned int* __restrict__ h16, float* __restrict__ agg,
    const unsigned short* __restrict__ WnB, const float* __restrict__ biasv,
    unsigned int* __restrict__ Pdst, unsigned int* __restrict__ Psrc, int mode, int N) {
  const int tid = threadIdx.x;
  const int wv = tid >> 6;
  const int lane = tid & 63;
  const int q = lane >> 4;
  const int n = lane & 15;
  const int nb = blockIdx.x * 32 + (wv >> 1) * 16;
  const int srcwave = wv & 1;
  const int ctile0 = srcwave * 16;

  const bool valid = (nb + n) < N;
  int anode = nb + n;
  if (anode >= N) anode = N - 1;
  unsigned int* hp = h16 + (size_t)anode * 64;

  short8 a[4];
  if (mode == 0) {
    const float* ep = emb + (size_t)x[anode] * HID;
#pragma unroll
    for (int kt = 0; kt < 4; ++kt) {
      const float4 e0 = *(const float4*)&ep[kt * 32 + q * 8];
      const float4 e1 = *(const float4*)&ep[kt * 32 + q * 8 + 4];
      if (valid && !srcwave) {
        uint4 hv;
        hv.x = pk_f16(e0.x, e0.y);
        hv.y = pk_f16(e0.z, e0.w);
        hv.z = pk_f16(e1.x, e1.y);
        hv.w = pk_f16(e1.z, e1.w);
        *(uint4*)&hp[kt * 16 + q * 4] = hv;
      }
      union { short8 s8; unsigned int u32[4]; } au;
      au.u32[0] = pk_bf16(e0.x, e0.y);
      au.u32[1] = pk_bf16(e0.z, e0.w);
      au.u32[2] = pk_bf16(e1.x, e1.y);
      au.u32[3] = pk_bf16(e1.z, e1.w);
      a[kt] = au.s8;
    }
  } else {
    float* ap = agg + (size_t)anode * HID;
    uint4 hnew[4];
#pragma unroll
    for (int kt = 0; kt < 4; ++kt) {
      const uint4 hv = *(const uint4*)&hp[kt * 16 + q * 4];
      const float2 h0 = __half22float2(*reinterpret_cast<const __half2*>(&hv.x));
      const float2 h1 = __half22float2(*reinterpret_cast<const __half2*>(&hv.y));
      const float2 h2 = __half22float2(*reinterpret_cast<const __half2*>(&hv.z));
      const float2 h3 = __half22float2(*reinterpret_cast<const __half2*>(&hv.w));
      const float4 g0 = *(const float4*)&ap[kt * 32 + q * 8];
      const float4 g1 = *(const float4*)&ap[kt * 32 + q * 8 + 4];
      const float e0 = fmaxf(h0.x + g0.x, 0.f);
      const float e1 = fmaxf(h0.y + g0.y, 0.f);
      const float e2 = fmaxf(h1.x + g0.z, 0.f);
      const float e3 = fmaxf(h1.y + g0.w, 0.f);
      const float e4 = fmaxf(h2.x + g1.x, 0.f);
      const float e5 = fmaxf(h2.y + g1.y, 0.f);
      const float e6 = fmaxf(h3.x + g1.z, 0.f);
      const float e7 = fmaxf(h3.y + g1.w, 0.f);
      hnew[kt].x = pk_f16(e0, e1);
      hnew[kt].y = pk_f16(e2, e3);
      hnew[kt].z = pk_f16(e4, e5);
      hnew[kt].w = pk_f16(e6, e7);
      union { short8 s8; unsigned int u32[4]; } au;
      au.u32[0] = pk_bf16(e0, e1);
      au.u32[1] = pk_bf16(e2, e3);
      au.u32[2] = pk_bf16(e4, e5);
      au.u32[3] = pk_bf16(e6, e7);
      a[kt] = au.s8;
    }
    __syncthreads();  // all h/agg reads done before in-place writes (race fix R11)
    if (valid && !srcwave) {
      const float4 z4 = {0.f, 0.f, 0.f, 0.f};
#pragma unroll
      for (int kt = 0; kt < 4; ++kt) {
        *(uint4*)&hp[kt * 16 + q * 4] = hnew[kt];
        *(float4*)&ap[kt * 32 + q * 8] = z4;       // re-zero agg for next layer
        *(float4*)&ap[kt * 32 + q * 8 + 4] = z4;
      }
    }
  }

  const short8* WnB8 = (const short8*)WnB;
  f32x4 acc[16];
#pragma unroll
  for (int tc = 0; tc < 16; ++tc) acc[tc] = (f32x4){0.f, 0.f, 0.f, 0.f};

#pragma unroll
  for (int tc = 0; tc < 16; ++tc) {
#pragma unroll
    for (int kt = 0; kt < 4; ++kt) {
      short8 b = WnB8[((size_t)((ctile0 + tc) * 4 + kt)) * 64 + lane];
      acc[tc] = __builtin_amdgcn_mfma_f32_16x16x32_bf16(a[kt], b, acc[tc], 0, 0, 0);
    }
  }

  // SIGMA epilogue: lane (q,n) emits channels c=g2*16+n for g2=0..7 at positions
  // n*8+g2 -> two contiguous uint4 stores per node-row.
  if (!srcwave) {
#pragma unroll
    for (int r = 0; r < 4; ++r) {
      const int node = nb + q * 4 + r;
      if (node < N) {
        unsigned int o[8];
#pragma unroll
        for (int g2 = 0; g2 < 8; ++g2) {
          const int c = g2 * 16 + n;
          o[g2] = pk_f16(acc[2 * g2][r] + biasv[2 * c], acc[2 * g2 + 1][r] + biasv[2 * c + 1]);
        }
        *(uint4*)&Pdst[(size_t)node * 128 + n * 8] = make_uint4(o[0], o[1], o[2], o[3]);
        *(uint4*)&Pdst[(size_t)node * 128 + n * 8 + 4] = make_uint4(o[4], o[5], o[6], o[7]);
      }
    }
  } else {
#pragma unroll
    for (int r = 0; r < 4; ++r) {
      const int node = nb + q * 4 + r;
      if (node < N) {
        unsigned int o[8];
#pragma unroll
        for (int g2 = 0; g2 < 8; ++g2) {
          o[g2] = pk_f16(acc[2 * g2][r], acc[2 * g2 + 1][r]);
        }
        *(uint4*)&Psrc[(size_t)node * 128 + n * 8] = make_uint4(o[0], o[1], o[2], o[3]);
        *(uint4*)&Psrc[(size_t)node * 128 + n * 8 + 4] = make_uint4(o[4], o[5], o[6], o[7]);
      }
    }
  }
}

// ---------------- MFMA edge kernel, EPB=64 / 256 threads ----------------
// Phase 2: contiguous 32B P gathers -> spd = ps+pd (f16); unpacked spd seeds the
// MFMA C-operand; fused activation; paired f16 act -> LDS.
// Phase 3 (R8 form, measured best): wave-0 ballot-scan groups; group-per-wave
// round-robin; ONE flush per group (boundary groups atomic, interior plain).
// R10's run-split flushed spanning groups twice (WRITE 31->48MB, +4us) -- reverted.
__global__ __launch_bounds__(256) void edge_mfma(
    const unsigned int* __restrict__ Pdst, const unsigned int* __restrict__ Psrc,
    const unsigned short* __restrict__ eaB, const unsigned short* __restrict__ WtB,
    const int2* __restrict__ se2, float* __restrict__ agg) {
  __shared__ unsigned int actL[EPB * SROWA2];   // 16.5 KB (64 pairs/edge)
  __shared__ int dstL[EPB];
  __shared__ int grpStart[EPB + 1];
  __shared__ int sndS;

  const int tid = threadIdx.x;
  const int base = blockIdx.x * EPB;
  const int lane = tid & 63;
  const int wv = tid >> 6;        // 0..3
  const int q = lane >> 4;
  const int n = lane & 15;
  const int rowb = wv * 16 + q * 4;

  // ---- Phase 1: wave-0 ballot-scan of sorted dsts -> groups (LDS) ----
  if (tid < EPB) {
    int2 sd = se2[base + tid];
    dstL[tid] = sd.y;
    int d = sd.y;
    int dprev = __shfl_up(d, 1);
    int flag = (tid == 0 || dprev != d) ? 1 : 0;
    unsigned long long mask = __ballot(flag);
    unsigned long long below = (lane == 63) ? ~0ull : ((1ull << (lane + 1)) - 1);
    int slot = __popcll(mask & below) - 1;
    if (flag) grpStart[slot] = tid;
    if (tid == 0) {
      int nd = __popcll(mask);
      sndS = nd;
      grpStart[nd] = EPB;
    }
  }

  // ---- Phase 2: contiguous P gathers -> spd; C-seeded MFMA; fused activation ----
  const short8 afrag = *(const short8*)&eaB[(size_t)(base + wv * 16 + n) * 32 + q * 8];

  uint4 spd[8];  // [r*2 + half]: ps+pd for this lane's 8 channels of 4 edges
#pragma unroll
  for (int r = 0; r < 4; ++r) {
    const int2 sd = se2[base + rowb + r];
    const uint4* ps4 = (const uint4*)(Psrc + (size_t)sd.x * 128 + n * 8);
    const uint4* pd4 = (const uint4*)(Pdst + (size_t)sd.y * 128 + n * 8);
    const uint4 s0 = ps4[0], s1 = ps4[1];
    const uint4 d0 = pd4[0], d1 = pd4[1];
    spd[r * 2].x = pk_add_f16(s0.x, d0.x);
    spd[r * 2].y = pk_add_f16(s0.y, d0.y);
    spd[r * 2].z = pk_add_f16(s0.z, d0.z);
    spd[r * 2].w = pk_add_f16(s0.w, d0.w);
    spd[r * 2 + 1].x = pk_add_f16(s1.x, d1.x);
    spd[r * 2 + 1].y = pk_add_f16(s1.y, d1.y);
    spd[r * 2 + 1].z = pk_add_f16(s1.z, d1.z);
    spd[r * 2 + 1].w = pk_add_f16(s1.w, d1.w);
  }

  const short8* WtB8 = (const short8*)WtB;
  float va[4][4];   // t<4 products, statically indexed (fully unrolled)
#pragma unroll
  for (int t = 0; t < 8; ++t) {
    f32x4 cinf, cins;
#pragma unroll
    for (int r = 0; r < 4; ++r) {
      const uint4 v = spd[r * 2 + (t >> 2)];
      const unsigned int sv = ((t & 3) == 0) ? v.x : ((t & 3) == 1) ? v.y
                             : ((t & 3) == 2) ? v.z : v.w;
      const float2 pz = __half22float2(*reinterpret_cast<const __half2*>(&sv));
      cinf[r] = pz.x;
      cins[r] = pz.y;
    }
    short8 bfr = WtB8[t * 64 + lane];
    short8 bsr = WtB8[(8 + t) * 64 + lane];
    f32x4 cf = __builtin_amdgcn_mfma_f32_16x16x32_bf16(afrag, bfr, cinf, 0, 0, 0);
    f32x4 cs = __builtin_amdgcn_mfma_f32_16x16x32_bf16(afrag, bsr, cins, 0, 0, 0);
#pragma unroll
    for (int r = 0; r < 4; ++r) {
      const float sig = __builtin_amdgcn_rcpf(1.f + aexp2(cf[r]));
      const float sp = fmaxf(cs[r], 0.f) + alog2(1.f + aexp2_nabs(cs[r]));
      const float av = sig * sp;
      if (t < 4) {
        va[t][r] = av;
      } else {
        actL[(rowb + r) * SROWA2 + (t - 4) * 16 + n] = pk_f16(va[t - 4][r], av);
      }
    }
  }
  __syncthreads();

  // ---- Phase 3: segmented reduction per group; lane owns channels (lane, lane+64) ----
  const int nd = sndS;
  for (int g = wv; g < nd; g += 4) {
    const int jb = grpStart[g];
    const int je = grpStart[g + 1];
    const int d = __builtin_amdgcn_readfirstlane(dstL[jb]);
    float a0 = 0.f, a1 = 0.f;
    unsigned int av_nx = actL[jb * SROWA2 + lane];
    for (int j = jb; j < je; ++j) {
      const unsigned int av = av_nx;
      const int jn = (j + 1 < je) ? (j + 1) : j;
      av_nx = actL[jn * SROWA2 + lane];
      const float2 a2 = __half22float2(*reinterpret_cast<const __half2*>(&av));
      a0 += a2.x;
      a1 += a2.y;
    }
    a0 *= 0.6931471805599453f;  // restore ln2 once per group
    a1 *= 0.6931471805599453f;
    float* ap0 = agg + (size_t)d * HID + lane;
    float* ap1 = ap0 + 64;
    if (g == 0 || g == nd - 1) {
      atomicAdd(ap0, a0);
      atomicAdd(ap1, a1);
    } else {
      *ap0 = a0;
      *ap1 = a1;
    }
  }
}

// ---------------- pooling: batch is SORTED -> run-detection, few atomics ----------------
__global__ __launch_bounds__(256) void pool_kernel(
    const unsigned int* __restrict__ h16, const float* __restrict__ agg,
    const int* __restrict__ batch, float* __restrict__ sums, float* __restrict__ counts) {
  __shared__ int gidL[64];
  __shared__ int grpS[65];
  __shared__ int sndP;

  const int tid = threadIdx.x;
  const int lane = tid & 63;
  const int wv = tid >> 6;
  const int nb = blockIdx.x * 64;
  int nvalid = NNODES - nb;
  if (nvalid > 64) nvalid = 64;

  if (tid < 64) {
    int node = nb + tid;
    int g = batch[node < NNODES ? node : NNODES - 1];
    gidL[tid] = g;
    int gprev = __shfl_up(g, 1);
    int flag = (tid < nvalid && (tid == 0 || gprev != g)) ? 1 : 0;
    unsigned long long mask = __ballot(flag);
    int slot = __popcll(mask & ((lane == 63) ? ~0ull : ((1ull << (lane + 1)) - 1))) - 1;
    if (flag) grpS[slot] = tid;
    if (tid == 0) {
      int nd = __popcll(mask);
      sndP = nd;
      grpS[nd] = nvalid;
    }
  }
  __syncthreads();

  const int nd = sndP;
  for (int g = wv; g < nd; g += 4) {
    const int jb = grpS[g];
    const int je = grpS[g + 1];
    const int gid = __builtin_amdgcn_readfirstlane(gidL[jb]);
    float a0 = 0.f, a1 = 0.f;
    for (int j = jb; j < je; ++j) {
      const unsigned int hv = h16[(size_t)(nb + j) * 64 + lane];
      const float2 hf = __half22float2(*reinterpret_cast<const __half2*>(&hv));
      const float2 av = *(const float2*)&agg[(size_t)(nb + j) * HID + 2 * lane];
      a0 += fmaxf(hf.x + av.x, 0.f);
      a1 += fmaxf(hf.y + av.y, 0.f);
    }
    float* sp = sums + (size_t)gid * HID + 2 * lane;
    const bool bnd = (g == 0 || g == nd - 1);
    if (bnd) {
      atomicAdd(sp, a0);
      atomicAdd(sp + 1, a1);
    } else {
      *(float2*)sp = make_float2(a0, a1);
    }
    if (lane == 0) {
      if (bnd) atomicAdd(&counts[gid], (float)(je - jb));
      else counts[gid] = (float)(je - jb);
    }
  }
}

// ---------------- out[g] = (sums[g]/max(cnt,1)) @ Wlin + blin ----------------
__global__ __launch_bounds__(128) void final_kernel(
    const float* __restrict__ sums, const float* __restrict__ counts,
    const float* __restrict__ Wlin, const float* __restrict__ blin,
    float* __restrict__ out) {
  int g = blockIdx.x;
  int c = threadIdx.x;
  __shared__ float pool[HID];
  float cnt = counts[g];
  cnt = cnt > 1.f ? cnt : 1.f;
  pool[c] = sums[(size_t)g * HID + c] / cnt;
  __syncthreads();
  float acc = blin[c];
#pragma unroll 8
  for (int k = 0; k < HID; ++k) acc = fmaf(pool[k], Wlin[k * HID + c], acc);
  out[(size_t)g * HID + c] = acc;
}

extern "C" void kernel_launch(void* const* d_in, const int* in_sizes, int n_in,
                              void* d_out, int out_size, void* d_ws, size_t ws_size,
                              hipStream_t stream) {
  const int* x = (const int*)d_in[0];
  const int* eidx = (const int*)d_in[1];
  const float* eattr = (const float*)d_in[2];
  const int* batch = (const int*)d_in[3];
  const float* emb = (const float*)d_in[4];
  const float* Wf[3] = {(const float*)d_in[5], (const float*)d_in[9], (const float*)d_in[13]};
  const float* bf[3] = {(const float*)d_in[6], (const float*)d_in[10], (const float*)d_in[14]};
  const float* Ws[3] = {(const float*)d_in[7], (const float*)d_in[11], (const float*)d_in[15]};
  const float* bs[3] = {(const float*)d_in[8], (const float*)d_in[12], (const float*)d_in[16]};
  const float* Wlin = (const float*)d_in[17];
  const float* blin = (const float*)d_in[18];
  const int* srcp = eidx;
  const int* dstp = eidx + NEDGES;

  float* wsf = (float*)d_ws;
  float* hF = wsf;                                   // N*128 reserved (N*64 uints used)
  float* PdstF = hF + (size_t)NNODES * HID;          // N*256 reserved (N*128 uints used)
  float* agg = PdstF + (size_t)NNODES * 256;         // N*128
  float* sums = agg + (size_t)NNODES * HID;          // 500*128
  float* counts = sums + (size_t)NGRAPH * HID;       // 500
  float* biasv3 = counts + NGRAPH;                   // 3*256
  unsigned int* Psrc = (unsigned int*)(biasv3 + 768);  // N*128 uint packed fp16
  unsigned short* WtB3 = (unsigned short*)(Psrc + (size_t)NNODES * 128);  // 3*8192
  unsigned short* WnB3 = WtB3 + 3 * 8192;            // 3*65536
  unsigned short* eaB = WnB3 + 3 * 65536;            // NEDGES*32 bf16
  int2* se2 = (int2*)(eaB + (size_t)NEDGES * 32);    // 800000 int2
  int* deg = (int*)(se2 + NEDGES);                   // 50000
  int* cursor = deg + NNODES;                        // 50000
  int* bsum = cursor + NNODES;                       // 196
  int* bpre = bsum + NB_SCAN;                        // 196
  unsigned int* Pdst = (unsigned int*)PdstF;         // N*128 uint packed fp16
  unsigned int* h16 = (unsigned int*)hF;             // N*64 uint packed f16 pairs

  // --- weight prep (all 3 layers, one launch) ---
  dim3 pgrid(288, 3);
  prep_all<<<pgrid, 256, 0, stream>>>(Wf[0], Ws[0], bf[0], bs[0],
                                      Wf[1], Ws[1], bf[1], bs[1],
                                      Wf[2], Ws[2], bf[2], bs[2],
                                      WtB3, WnB3, biasv3);

  // --- CSR build (edges layer-invariant: once per call) ---
  hipMemsetAsync(deg, 0, NNODES * sizeof(int), stream);
  deg_hist<<<(NEDGES + 255) / 256, 256, 0, stream>>>(dstp, deg);
  scan_block<<<NB_SCAN, 256, 0, stream>>>(deg, bsum);
  scan_top<<<1, 256, 0, stream>>>(bsum, bpre);
  scan_final<<<NB_SCAN, 256, 0, stream>>>(deg, bpre, cursor);
  scatter_edges_pack<<<(NEDGES + 255) / 256, 256, 0, stream>>>(srcp, dstp, eattr, cursor,
                                                               se2, eaB);

  // single agg zero: layer>=1 re-zeroed inside node_mfma mode 1
  hipMemsetAsync(agg, 0, (size_t)NNODES * HID * sizeof(float), stream);

  const int nblk_node = (NNODES + 31) / 32;  // 1563
  for (int l = 0; l < 3; ++l) {
    node_mfma<<<nblk_node, 256, 0, stream>>>(x, emb, h16, agg, WnB3 + l * 65536,
                                             biasv3 + l * 256, Pdst, Psrc,
                                             l > 0 ? 1 : 0, NNODES);
    edge_mfma<<<NEBLK, 256, 0, stream>>>(Pdst, Psrc, eaB, WtB3 + l * 8192, se2, agg);
  }

  hipMemsetAsync(sums, 0, (size_t)(NGRAPH * HID + NGRAPH) * sizeof(float), stream);
  pool_kernel<<<(NNODES + 63) / 64, 256, 0, stream>>>(h16, agg, batch, sums, counts);
  final_kernel<<<NGRAPH, 128, 0, stream>>>(sums, counts, Wlin, blin, (float*)d_out);
}